// Round 6
// baseline (688.592 us; speedup 1.0000x reference)
//
#include <hip/hip_runtime.h>
#include <math.h>

#define NFFT 256
#define NBINS 129
#define HOP 64
#define NFRAMES 65
#define NB 64
#define LX 4096
#define LH 2048
#define LY 1024
#define NCH 64
#define NBR 3
#define NE 8

#define POOLED_BYTES (NB * NBINS * 4)
#define WT_OFF 40960                 // byte offset of wT in ws
#define WT_PER 98304                 // floats per branch tensor (8*64*3*64)

typedef float f4u __attribute__((ext_vector_type(4), aligned(4)));

// ---------------- STFT magnitude + frame-mean pooling (phasor DFT) --------
// grid (65 frames, 64 batch), 128 threads. Bin k on tid k; Nyquist on tid 0.
__global__ __launch_bounds__(128) void stft_kernel(const float* __restrict__ x,
                                                   float* __restrict__ pooled) {
    __shared__ float xw[NFFT];
    const int f = blockIdx.x, b = blockIdx.y;
    const int tid = threadIdx.x;

    for (int n = tid; n < NFFT; n += 128) {
        float ang = (float)(2.0 * 3.14159265358979323846 / 256.0) * (float)n;
        float s, c;
        sincosf(ang, &s, &c);
        float win = 0.5f - 0.5f * c;              // Hann
        int q = f * HOP + n - 128;                // position in x coords
        int xi = q < 0 ? -q : (q >= LX ? (2 * LX - 2 - q) : q);  // reflect
        xw[n] = x[b * LX + xi] * win;
    }
    __syncthreads();

    const int k = tid;                            // bin 0..127
    float ang = (float)(2.0 * 3.14159265358979323846 / 256.0) * (float)k;
    float s1, c1;
    sincosf(ang, &s1, &c1);
    float c = 1.f, s = 0.f;
    float re = 0.f, im = 0.f;
    float reN = 0.f, sgn = 1.f;                   // Nyquist bin (all lanes, redundant)
    for (int n = 0; n < NFFT; ++n) {
        float v = xw[n];
        re += v * c;
        im += v * s;
        reN += v * sgn;
        sgn = -sgn;
        float t = c * c1 - s * s1;
        s = c * s1 + s * c1;
        c = t;
    }
    atomicAdd(&pooled[b * NBINS + k], sqrtf(re * re + im * im));
    if (tid == 0) atomicAdd(&pooled[b * NBINS + 128], fabsf(reN));
}

// ---------------- Gating MLP + top-2 softmax ----------------
__global__ __launch_bounds__(256) void gating_kernel(
    const float* __restrict__ pooled,
    const float* __restrict__ Wg1, const float* __restrict__ bg1,
    const float* __restrict__ Wg2, const float* __restrict__ bg2,
    const float* __restrict__ Wg3, const float* __restrict__ bg3,
    int* __restrict__ inds, float* __restrict__ wts) {
    __shared__ float pl[NBINS];
    __shared__ float h1[256];
    __shared__ float h2[128];
    __shared__ float lg[NE];
    const int b = blockIdx.x, tid = threadIdx.x;

    if (tid < NBINS) pl[tid] = pooled[b * NBINS + tid] * (1.0f / (float)NFRAMES);
    __syncthreads();
    {
        float s = bg1[tid];
        for (int k = 0; k < NBINS; ++k) s += pl[k] * Wg1[k * 256 + tid];
        h1[tid] = fmaxf(s, 0.f);
    }
    __syncthreads();
    if (tid < 128) {
        float s = bg2[tid];
        for (int k = 0; k < 256; ++k) s += h1[k] * Wg2[k * 128 + tid];
        h2[tid] = fmaxf(s, 0.f);
    }
    __syncthreads();
    if (tid < NE) {
        float s = bg3[tid];
        for (int k = 0; k < 128; ++k) s += h2[k] * Wg3[k * NE + tid];
        lg[tid] = s;
    }
    __syncthreads();
    if (tid == 0) {
        int i0 = 0;
        float v0 = lg[0];
        for (int i = 1; i < NE; ++i)
            if (lg[i] > v0) { v0 = lg[i]; i0 = i; }
        int i1 = -1;
        float v1 = -3.0e38f;
        for (int i = 0; i < NE; ++i) {
            if (i == i0) continue;
            if (lg[i] > v1) { v1 = lg[i]; i1 = i; }
        }
        float e1 = expf(v1 - v0);
        float w0 = 1.f / (1.f + e1);
        inds[b * 2 + 0] = i0;
        inds[b * 2 + 1] = i1;
        wts[b * 2 + 0] = w0;
        wts[b * 2 + 1] = e1 * w0;
    }
}

// ---------------- Weight transpose: wT[t][e][cl][i][c2] <- wb[e][c2][cl][i]
__global__ __launch_bounds__(256) void reformat_wb(
    const float* __restrict__ wb3, const float* __restrict__ wb5,
    const float* __restrict__ wb7, float* __restrict__ wT) {
    int idx = blockIdx.x * 256 + threadIdx.x;
    if (idx >= 3 * WT_PER) return;
    int t = idx / WT_PER, r = idx % WT_PER;
    int c2 = r & 63;
    int i = (r >> 6) % 3;
    int cl = ((r >> 6) / 3) & 63;
    int e = r / 12288;
    const float* src = (t == 0) ? wb3 : (t == 1) ? wb5 : wb7;
    wT[idx] = src[((e * 64 + c2) * 64 + cl) * 3 + i];
}

// ---------------- Expert two-conv path, top-2 dispatched ----------------
// grid (u-tiles=4 of 256, branch=3, batch=64), 512 threads (8 waves).
// Wave w owns c2 block {8w..8w+7} (wave-uniform -> weights via scalar loads);
// lane owns 4 consecutive u. h tile in LDS with XOR bank swizzle; x read from
// global (L1-resident row); second-conv weights from wT via s_load.
#define UT 256
#define CCH 16
#define NG 129       // float4 groups of h positions (0..512)
#define HST 516      // words per hl row (129 groups * 4)

__device__ __forceinline__ int swz(int g) { return g ^ ((g >> 3) & 7); }

template <int KSZ>
__device__ __forceinline__ void phaseA_one(
    const float* __restrict__ xp, const float* __restrict__ wa,
    const float* __restrict__ ba, float* hl,
    int e, int c0, int cl, int g, int t0, int x0) {
    const int pbase = 4 * g;
    const int xg = x0 + 8 * g;
    float xv[16];
    if (xg >= 0 && xg + 15 < LX) {
        f4u a0 = *(const f4u*)&xp[xg];
        f4u a1 = *(const f4u*)&xp[xg + 4];
        f4u a2 = *(const f4u*)&xp[xg + 8];
        f4u a3 = *(const f4u*)&xp[xg + 12];
#pragma unroll
        for (int ii = 0; ii < 4; ++ii) {
            xv[ii] = a0[ii]; xv[4 + ii] = a1[ii];
            xv[8 + ii] = a2[ii]; xv[12 + ii] = a3[ii];
        }
    } else {
#pragma unroll
        for (int ii = 0; ii < 16; ++ii) {
            int xi = xg + ii;
            xv[ii] = (xi >= 0 && xi < LX) ? xp[xi] : 0.f;
        }
    }
    float wr[KSZ];
#pragma unroll
    for (int i = 0; i < KSZ; ++i) wr[i] = wa[(e * NCH + c0 + cl) * KSZ + i];
    float bv = ba[e * NCH + c0 + cl];
    float4 hv;
    float hm[4];
#pragma unroll
    for (int m = 0; m < 4; ++m) {
        float s = bv;
#pragma unroll
        for (int i = 0; i < KSZ; ++i) s += wr[i] * xv[2 * m + i];
        int t = t0 + pbase + m;
        hm[m] = (t >= 0 && t < LH) ? fmaxf(s, 0.f) : 0.f;
    }
    hv.x = hm[0]; hv.y = hm[1]; hv.z = hm[2]; hv.w = hm[3];
    *(float4*)&hl[cl * HST + 4 * swz(g)] = hv;
}

template <int KSZ>
__device__ __attribute__((always_inline)) void expert_body(
    const float* __restrict__ x,
    const float* __restrict__ wa, const float* __restrict__ ba,
    const float* __restrict__ wTbr, const float* __restrict__ bb,
    const int* __restrict__ inds, const float* __restrict__ wts,
    float* __restrict__ out, int br, float* hl) {
    const int u0 = blockIdx.x * UT;
    const int b = blockIdx.z;
    const int tid = threadIdx.x;
    const int pad = KSZ >> 1;

    const int t0 = 2 * u0 - 1;          // first h position needed
    const int x0 = 2 * t0 - pad;        // first x index needed

    const int lane = tid & 63;
    const int wv = __builtin_amdgcn_readfirstlane(tid >> 6);  // c2 block, uniform

    const float* xp = x + b * LX;
    const int ub = u0 + 4 * lane;
    const int swa = 4 * swz(2 * lane);
    const int swb = 4 * swz(2 * lane + 1);
    const int swc = 4 * swz(2 * lane + 2);

    float fin[8][4];
#pragma unroll
    for (int j = 0; j < 8; ++j)
#pragma unroll
        for (int m = 0; m < 4; ++m) fin[j][m] = 0.f;

    for (int slot = 0; slot < 2; ++slot) {
        const int e = __builtin_amdgcn_readfirstlane(inds[b * 2 + slot]);
        const float wj = wts[b * 2 + slot];
        const float* wTe = wTbr + e * 12288 + wv * 8;   // + cl*192 + i*64 + j

        float acc[8][4];
#pragma unroll
        for (int j = 0; j < 8; ++j) {
            float bbv = bb[e * NCH + wv * 8 + j];       // uniform -> s_load
#pragma unroll
            for (int m = 0; m < 4; ++m) acc[j][m] = bbv;
        }

        for (int c0 = 0; c0 < NCH; c0 += CCH) {
            __syncthreads();   // protect LDS from previous chunk's readers

            // phase A: first conv + relu into LDS. 16 cl x 128 groups main,
            // + 16-thread epilogue for group 128.
#pragma unroll
            for (int it = 0; it < 4; ++it) {
                int idx = tid + it * 512;
                phaseA_one<KSZ>(xp, wa, ba, hl, e, c0, idx >> 7, idx & 127,
                                t0, x0);
            }
            if (tid < CCH)
                phaseA_one<KSZ>(xp, wa, ba, hl, e, c0, tid, 128, t0, x0);
            __syncthreads();

            // phase C: 8 c2 x 4 u per lane; weights via scalar loads from wT.
#pragma unroll
            for (int cl = 0; cl < CCH; ++cl) {
                const float* wrow = wTe + (c0 + cl) * 192;
                float sw0[8], sw1[8], sw2[8];
#pragma unroll
                for (int j = 0; j < 8; ++j) {
                    sw0[j] = wrow[j];
                    sw1[j] = wrow[64 + j];
                    sw2[j] = wrow[128 + j];
                }
                float4 ha = *(const float4*)&hl[cl * HST + swa];
                float4 hb = *(const float4*)&hl[cl * HST + swb];
                float4 hc = *(const float4*)&hl[cl * HST + swc];
#pragma unroll
                for (int j = 0; j < 8; ++j) {
                    acc[j][0] += sw0[j] * ha.x + sw1[j] * ha.y + sw2[j] * ha.z;
                    acc[j][1] += sw0[j] * ha.z + sw1[j] * ha.w + sw2[j] * hb.x;
                    acc[j][2] += sw0[j] * hb.x + sw1[j] * hb.y + sw2[j] * hb.z;
                    acc[j][3] += sw0[j] * hb.z + sw1[j] * hb.w + sw2[j] * hc.x;
                }
            }
        }

#pragma unroll
        for (int j = 0; j < 8; ++j)
#pragma unroll
            for (int m = 0; m < 4; ++m)
                fin[j][m] += wj * fmaxf(acc[j][m], 0.f);
    }

#pragma unroll
    for (int j = 0; j < 8; ++j) {
        int c2 = wv * 8 + j;
        long row = (long)(b * 192 + br * 64 + c2) * LY;
        float4 o;
        o.x = fin[j][0]; o.y = fin[j][1]; o.z = fin[j][2]; o.w = fin[j][3];
        *(float4*)&out[row + ub] = o;
    }
}

__global__ __launch_bounds__(512, 2) void expert_kernel(
    const float* __restrict__ x,
    const float* __restrict__ wa3, const float* __restrict__ ba3,
    const float* __restrict__ bb3,
    const float* __restrict__ wa5, const float* __restrict__ ba5,
    const float* __restrict__ bb5,
    const float* __restrict__ wa7, const float* __restrict__ ba7,
    const float* __restrict__ bb7,
    const float* __restrict__ wT,
    const int* __restrict__ inds, const float* __restrict__ wts,
    float* __restrict__ out) {
    __shared__ float hl[CCH * HST];        // 33 KB

    const int br = blockIdx.y;
    if (br == 0)
        expert_body<3>(x, wa3, ba3, wT, bb3, inds, wts, out, 0, hl);
    else if (br == 1)
        expert_body<5>(x, wa5, ba5, wT + WT_PER, bb5, inds, wts, out, 1, hl);
    else
        expert_body<7>(x, wa7, ba7, wT + 2 * WT_PER, bb7, inds, wts, out, 2, hl);
}

extern "C" void kernel_launch(void* const* d_in, const int* in_sizes, int n_in,
                              void* d_out, int out_size, void* d_ws, size_t ws_size,
                              hipStream_t stream) {
    const float* x   = (const float*)d_in[0];
    const float* Wg1 = (const float*)d_in[1];
    const float* bg1 = (const float*)d_in[2];
    const float* Wg2 = (const float*)d_in[3];
    const float* bg2 = (const float*)d_in[4];
    const float* Wg3 = (const float*)d_in[5];
    const float* bg3 = (const float*)d_in[6];
    const float* wa3 = (const float*)d_in[7];
    const float* ba3 = (const float*)d_in[8];
    const float* wb3 = (const float*)d_in[9];
    const float* bb3 = (const float*)d_in[10];
    const float* wa5 = (const float*)d_in[11];
    const float* ba5 = (const float*)d_in[12];
    const float* wb5 = (const float*)d_in[13];
    const float* bb5 = (const float*)d_in[14];
    const float* wa7 = (const float*)d_in[15];
    const float* ba7 = (const float*)d_in[16];
    const float* wb7 = (const float*)d_in[17];
    const float* bb7 = (const float*)d_in[18];

    float* pooled = (float*)d_ws;
    int* inds = (int*)((char*)d_ws + POOLED_BYTES);
    float* wts = (float*)((char*)d_ws + POOLED_BYTES + 512);
    float* wT = (float*)((char*)d_ws + WT_OFF);

    hipMemsetAsync(d_ws, 0, POOLED_BYTES, stream);
    reformat_wb<<<(3 * WT_PER + 255) / 256, 256, 0, stream>>>(wb3, wb5, wb7, wT);
    stft_kernel<<<dim3(NFRAMES, NB), 128, 0, stream>>>(x, pooled);
    gating_kernel<<<NB, 256, 0, stream>>>(pooled, Wg1, bg1, Wg2, bg2, Wg3, bg3,
                                          inds, wts);
    expert_kernel<<<dim3(LY / UT, NBR, NB), 512, 0, stream>>>(
        x, wa3, ba3, bb3, wa5, ba5, bb5, wa7, ba7, bb7, wT,
        inds, wts, (float*)d_out);
}

// Round 7
// 389.859 us; speedup vs baseline: 1.7663x; 1.7663x over previous
//
#include <hip/hip_runtime.h>
#include <math.h>

#define NFFT 256
#define NBINS 129
#define HOP 64
#define NFRAMES 65
#define NB 64
#define LX 4096
#define LH 2048
#define LY 1024
#define NCH 64
#define NBR 3
#define NE 8

#define POOLED_BYTES (NB * NBINS * 4)
#define WT_OFF 40960                 // byte offset of wT in ws
#define WT_PER 98304                 // floats per branch tensor (8*64*3*64)

typedef float f4u __attribute__((ext_vector_type(4), aligned(4)));

// ---------------- STFT magnitude + frame-mean pooling (phasor DFT) --------
__global__ __launch_bounds__(128) void stft_kernel(const float* __restrict__ x,
                                                   float* __restrict__ pooled) {
    __shared__ float xw[NFFT];
    const int f = blockIdx.x, b = blockIdx.y;
    const int tid = threadIdx.x;

    for (int n = tid; n < NFFT; n += 128) {
        float ang = (float)(2.0 * 3.14159265358979323846 / 256.0) * (float)n;
        float s, c;
        sincosf(ang, &s, &c);
        float win = 0.5f - 0.5f * c;              // Hann
        int q = f * HOP + n - 128;                // position in x coords
        int xi = q < 0 ? -q : (q >= LX ? (2 * LX - 2 - q) : q);  // reflect
        xw[n] = x[b * LX + xi] * win;
    }
    __syncthreads();

    const int k = tid;                            // bin 0..127
    float ang = (float)(2.0 * 3.14159265358979323846 / 256.0) * (float)k;
    float s1, c1;
    sincosf(ang, &s1, &c1);
    float c = 1.f, s = 0.f;
    float re = 0.f, im = 0.f;
    float reN = 0.f, sgn = 1.f;                   // Nyquist (redundant per lane)
    for (int n = 0; n < NFFT; ++n) {
        float v = xw[n];
        re += v * c;
        im += v * s;
        reN += v * sgn;
        sgn = -sgn;
        float t = c * c1 - s * s1;
        s = c * s1 + s * c1;
        c = t;
    }
    atomicAdd(&pooled[b * NBINS + k], sqrtf(re * re + im * im));
    if (tid == 0) atomicAdd(&pooled[b * NBINS + 128], fabsf(reN));
}

// ---------------- Gating MLP + top-2 softmax ----------------
__global__ __launch_bounds__(256) void gating_kernel(
    const float* __restrict__ pooled,
    const float* __restrict__ Wg1, const float* __restrict__ bg1,
    const float* __restrict__ Wg2, const float* __restrict__ bg2,
    const float* __restrict__ Wg3, const float* __restrict__ bg3,
    int* __restrict__ inds, float* __restrict__ wts) {
    __shared__ float pl[NBINS];
    __shared__ float h1[256];
    __shared__ float h2[128];
    __shared__ float lg[NE];
    const int b = blockIdx.x, tid = threadIdx.x;

    if (tid < NBINS) pl[tid] = pooled[b * NBINS + tid] * (1.0f / (float)NFRAMES);
    __syncthreads();
    {
        float s = bg1[tid];
        for (int k = 0; k < NBINS; ++k) s += pl[k] * Wg1[k * 256 + tid];
        h1[tid] = fmaxf(s, 0.f);
    }
    __syncthreads();
    if (tid < 128) {
        float s = bg2[tid];
        for (int k = 0; k < 256; ++k) s += h1[k] * Wg2[k * 128 + tid];
        h2[tid] = fmaxf(s, 0.f);
    }
    __syncthreads();
    if (tid < NE) {
        float s = bg3[tid];
        for (int k = 0; k < 128; ++k) s += h2[k] * Wg3[k * NE + tid];
        lg[tid] = s;
    }
    __syncthreads();
    if (tid == 0) {
        int i0 = 0;
        float v0 = lg[0];
        for (int i = 1; i < NE; ++i)
            if (lg[i] > v0) { v0 = lg[i]; i0 = i; }
        int i1 = -1;
        float v1 = -3.0e38f;
        for (int i = 0; i < NE; ++i) {
            if (i == i0) continue;
            if (lg[i] > v1) { v1 = lg[i]; i1 = i; }
        }
        float e1 = expf(v1 - v0);
        float w0 = 1.f / (1.f + e1);
        inds[b * 2 + 0] = i0;
        inds[b * 2 + 1] = i1;
        wts[b * 2 + 0] = w0;
        wts[b * 2 + 1] = e1 * w0;
    }
}

// ---------------- Weight transpose: wT[t][e][cl][i][c2] <- wb[e][c2][cl][i]
__global__ __launch_bounds__(256) void reformat_wb(
    const float* __restrict__ wb3, const float* __restrict__ wb5,
    const float* __restrict__ wb7, float* __restrict__ wT) {
    int idx = blockIdx.x * 256 + threadIdx.x;
    if (idx >= 3 * WT_PER) return;
    int t = idx / WT_PER, r = idx % WT_PER;
    int c2 = r & 63;
    int i = (r >> 6) % 3;
    int cl = ((r >> 6) / 3) & 63;
    int e = r / 12288;
    const float* src = (t == 0) ? wb3 : (t == 1) ? wb5 : wb7;
    wT[idx] = src[((e * 64 + c2) * 64 + cl) * 3 + i];
}

// ---------------- Expert two-conv path, top-2 dispatched ----------------
// grid (u-tiles=4 of 256, branch=3, batch=64), 512 threads (8 waves).
// Wave w owns c2 block {8w..8w+7} (wave-uniform -> weights via scalar loads);
// lane owns 4 consecutive u. h tile in LDS with XOR bank swizzle; x from
// global (L1-resident row). Unroll pragmas bound the scheduler's load
// hoisting (full unroll spilled: R6 WRITE_SIZE 530 MB).
#define UT 256
#define CCH 16
#define NG 129       // float4 groups of h positions (0..512)
#define HST 516      // words per hl row (129 groups * 4)

__device__ __forceinline__ int swz(int g) { return g ^ ((g >> 3) & 7); }

template <int KSZ>
__device__ __forceinline__ void phaseA_one(
    const float* __restrict__ xp, const float* __restrict__ wa,
    const float* __restrict__ ba, float* hl,
    int e, int c0, int cl, int g, int t0, int x0) {
    const int pbase = 4 * g;
    const int xg = x0 + 8 * g;
    float xv[16];
    if (xg >= 0 && xg + 15 < LX) {
        f4u a0 = *(const f4u*)&xp[xg];
        f4u a1 = *(const f4u*)&xp[xg + 4];
        f4u a2 = *(const f4u*)&xp[xg + 8];
        f4u a3 = *(const f4u*)&xp[xg + 12];
#pragma unroll
        for (int ii = 0; ii < 4; ++ii) {
            xv[ii] = a0[ii]; xv[4 + ii] = a1[ii];
            xv[8 + ii] = a2[ii]; xv[12 + ii] = a3[ii];
        }
    } else {
#pragma unroll
        for (int ii = 0; ii < 16; ++ii) {
            int xi = xg + ii;
            xv[ii] = (xi >= 0 && xi < LX) ? xp[xi] : 0.f;
        }
    }
    float wr[KSZ];
#pragma unroll
    for (int i = 0; i < KSZ; ++i) wr[i] = wa[(e * NCH + c0 + cl) * KSZ + i];
    float bv = ba[e * NCH + c0 + cl];
    float4 hv;
    float hm[4];
#pragma unroll
    for (int m = 0; m < 4; ++m) {
        float s = bv;
#pragma unroll
        for (int i = 0; i < KSZ; ++i) s += wr[i] * xv[2 * m + i];
        int t = t0 + pbase + m;
        hm[m] = (t >= 0 && t < LH) ? fmaxf(s, 0.f) : 0.f;
    }
    hv.x = hm[0]; hv.y = hm[1]; hv.z = hm[2]; hv.w = hm[3];
    *(float4*)&hl[cl * HST + 4 * swz(g)] = hv;
}

template <int KSZ>
__device__ __attribute__((always_inline)) void expert_body(
    const float* __restrict__ x,
    const float* __restrict__ wa, const float* __restrict__ ba,
    const float* __restrict__ wTbr, const float* __restrict__ bb,
    const int* __restrict__ inds, const float* __restrict__ wts,
    float* __restrict__ out, int br, float* hl) {
    const int u0 = blockIdx.x * UT;
    const int b = blockIdx.z;
    const int tid = threadIdx.x;
    const int pad = KSZ >> 1;

    const int t0 = 2 * u0 - 1;          // first h position needed
    const int x0 = 2 * t0 - pad;        // first x index needed

    const int lane = tid & 63;
    const int wv = __builtin_amdgcn_readfirstlane(tid >> 6);  // c2 block, uniform

    const float* xp = x + b * LX;
    const int ub = u0 + 4 * lane;
    const int swa = 4 * swz(2 * lane);
    const int swb = 4 * swz(2 * lane + 1);
    const int swc = 4 * swz(2 * lane + 2);

    float fin[8][4];
#pragma unroll
    for (int j = 0; j < 8; ++j)
#pragma unroll
        for (int m = 0; m < 4; ++m) fin[j][m] = 0.f;

#pragma unroll 1
    for (int slot = 0; slot < 2; ++slot) {
        const int e = __builtin_amdgcn_readfirstlane(inds[b * 2 + slot]);
        const float wj = wts[b * 2 + slot];
        const float* wTe = wTbr + e * 12288 + wv * 8;   // + cl*192 + i*64 + j

        float acc[8][4];
#pragma unroll
        for (int j = 0; j < 8; ++j) {
            float bbv = bb[e * NCH + wv * 8 + j];       // uniform -> s_load
#pragma unroll
            for (int m = 0; m < 4; ++m) acc[j][m] = bbv;
        }

#pragma unroll 1
        for (int c0 = 0; c0 < NCH; c0 += CCH) {
            __syncthreads();   // protect LDS from previous chunk's readers

            // phase A: first conv + relu into LDS. 16 cl x 128 groups main,
            // + 16-thread epilogue for group 128.
#pragma unroll 1
            for (int it = 0; it < 4; ++it) {
                int idx = tid + it * 512;
                phaseA_one<KSZ>(xp, wa, ba, hl, e, c0, idx >> 7, idx & 127,
                                t0, x0);
            }
            if (tid < CCH)
                phaseA_one<KSZ>(xp, wa, ba, hl, e, c0, tid, 128, t0, x0);
            __syncthreads();

            // phase C: 8 c2 x 4 u per lane; weights via scalar loads from wT.
#pragma unroll 2
            for (int cl = 0; cl < CCH; ++cl) {
                const float* wrow = wTe + (c0 + cl) * 192;
                float sw0[8], sw1[8], sw2[8];
#pragma unroll
                for (int j = 0; j < 8; ++j) {
                    sw0[j] = wrow[j];
                    sw1[j] = wrow[64 + j];
                    sw2[j] = wrow[128 + j];
                }
                float4 ha = *(const float4*)&hl[cl * HST + swa];
                float4 hb = *(const float4*)&hl[cl * HST + swb];
                float4 hc = *(const float4*)&hl[cl * HST + swc];
#pragma unroll
                for (int j = 0; j < 8; ++j) {
                    acc[j][0] += sw0[j] * ha.x + sw1[j] * ha.y + sw2[j] * ha.z;
                    acc[j][1] += sw0[j] * ha.z + sw1[j] * ha.w + sw2[j] * hb.x;
                    acc[j][2] += sw0[j] * hb.x + sw1[j] * hb.y + sw2[j] * hb.z;
                    acc[j][3] += sw0[j] * hb.z + sw1[j] * hb.w + sw2[j] * hc.x;
                }
            }
        }

#pragma unroll
        for (int j = 0; j < 8; ++j)
#pragma unroll
            for (int m = 0; m < 4; ++m)
                fin[j][m] += wj * fmaxf(acc[j][m], 0.f);
    }

#pragma unroll
    for (int j = 0; j < 8; ++j) {
        int c2 = wv * 8 + j;
        long row = (long)(b * 192 + br * 64 + c2) * LY;
        float4 o;
        o.x = fin[j][0]; o.y = fin[j][1]; o.z = fin[j][2]; o.w = fin[j][3];
        *(float4*)&out[row + ub] = o;
    }
}

__global__ __launch_bounds__(512, 2) void expert_kernel(
    const float* __restrict__ x,
    const float* __restrict__ wa3, const float* __restrict__ ba3,
    const float* __restrict__ bb3,
    const float* __restrict__ wa5, const float* __restrict__ ba5,
    const float* __restrict__ bb5,
    const float* __restrict__ wa7, const float* __restrict__ ba7,
    const float* __restrict__ bb7,
    const float* __restrict__ wT,
    const int* __restrict__ inds, const float* __restrict__ wts,
    float* __restrict__ out) {
    __shared__ float hl[CCH * HST];        // 33 KB

    const int br = blockIdx.y;
    if (br == 0)
        expert_body<3>(x, wa3, ba3, wT, bb3, inds, wts, out, 0, hl);
    else if (br == 1)
        expert_body<5>(x, wa5, ba5, wT + WT_PER, bb5, inds, wts, out, 1, hl);
    else
        expert_body<7>(x, wa7, ba7, wT + 2 * WT_PER, bb7, inds, wts, out, 2, hl);
}

extern "C" void kernel_launch(void* const* d_in, const int* in_sizes, int n_in,
                              void* d_out, int out_size, void* d_ws, size_t ws_size,
                              hipStream_t stream) {
    const float* x   = (const float*)d_in[0];
    const float* Wg1 = (const float*)d_in[1];
    const float* bg1 = (const float*)d_in[2];
    const float* Wg2 = (const float*)d_in[3];
    const float* bg2 = (const float*)d_in[4];
    const float* Wg3 = (const float*)d_in[5];
    const float* bg3 = (const float*)d_in[6];
    const float* wa3 = (const float*)d_in[7];
    const float* ba3 = (const float*)d_in[8];
    const float* wb3 = (const float*)d_in[9];
    const float* bb3 = (const float*)d_in[10];
    const float* wa5 = (const float*)d_in[11];
    const float* ba5 = (const float*)d_in[12];
    const float* wb5 = (const float*)d_in[13];
    const float* bb5 = (const float*)d_in[14];
    const float* wa7 = (const float*)d_in[15];
    const float* ba7 = (const float*)d_in[16];
    const float* wb7 = (const float*)d_in[17];
    const float* bb7 = (const float*)d_in[18];

    float* pooled = (float*)d_ws;
    int* inds = (int*)((char*)d_ws + POOLED_BYTES);
    float* wts = (float*)((char*)d_ws + POOLED_BYTES + 512);
    float* wT = (float*)((char*)d_ws + WT_OFF);

    hipMemsetAsync(d_ws, 0, POOLED_BYTES, stream);
    reformat_wb<<<(3 * WT_PER + 255) / 256, 256, 0, stream>>>(wb3, wb5, wb7, wT);
    stft_kernel<<<dim3(NFRAMES, NB), 128, 0, stream>>>(x, pooled);
    gating_kernel<<<NB, 256, 0, stream>>>(pooled, Wg1, bg1, Wg2, bg2, Wg3, bg3,
                                          inds, wts);
    expert_kernel<<<dim3(LY / UT, NBR, NB), 512, 0, stream>>>(
        x, wa3, ba3, bb3, wa5, ba5, bb5, wa7, ba7, bb7, wT,
        inds, wts, (float*)d_out);
}

// Round 8
// 339.495 us; speedup vs baseline: 2.0283x; 1.1484x over previous
//
#include <hip/hip_runtime.h>
#include <math.h>

#define NFFT 256
#define NBINS 129
#define HOP 64
#define NFRAMES 65
#define NB 64
#define LX 4096
#define LH 2048
#define LY 1024
#define NCH 64
#define NBR 3
#define NE 8

#define NFG 13                      // frame groups (5 frames each)
#define PART_STRIDE 132
#define PART_BYTES (NB * NFG * PART_STRIDE * 4)   // 439,296
#define WT_OFF 440320               // byte offset of wT in ws
#define WT_PER 98304                // floats per branch tensor (8*64*3*64)
#define IW_OFF 1703936              // inds/wts offset

// ---------------- STFT partial magnitudes + wT build ----------------
// grid (13 frame-groups, 64 batch), 128 threads. Each block: 5 frames,
// phasor DFT, per-bin partial sums (no atomics, no memset needed).
__global__ __launch_bounds__(128) void stft_kernel(
    const float* __restrict__ x,
    const float* __restrict__ wb3, const float* __restrict__ wb5,
    const float* __restrict__ wb7, float* __restrict__ wT,
    float* __restrict__ part) {
    __shared__ float xw[NFFT];
    const int g = blockIdx.x, b = blockIdx.y;
    const int tid = threadIdx.x;

    // fold the wb transpose here (independent of x): wT[t][e][cl][i][c2]
    {
        int bid = b * NFG + g;
        for (int idx = bid * 128 + tid; idx < 3 * WT_PER; idx += NB * NFG * 128) {
            int t = idx / WT_PER, r = idx % WT_PER;
            int c2 = r & 63;
            int i = (r >> 6) % 3;
            int cl = ((r >> 6) / 3) & 63;
            int e = r / 12288;
            const float* src = (t == 0) ? wb3 : (t == 1) ? wb5 : wb7;
            wT[idx] = src[((e * 64 + c2) * 64 + cl) * 3 + i];
        }
    }

    const int k = tid;
    float ang = (float)(2.0 * 3.14159265358979323846 / 256.0) * (float)k;
    float s1, c1;
    sincosf(ang, &s1, &c1);

    float acck = 0.f, accN = 0.f;
    for (int f0 = 0; f0 < 5; ++f0) {
        int f = g * 5 + f0;
        __syncthreads();            // xw reuse guard
        for (int n = tid; n < NFFT; n += 128) {
            float a2 = (float)(2.0 * 3.14159265358979323846 / 256.0) * (float)n;
            float sn, cn;
            sincosf(a2, &sn, &cn);
            float win = 0.5f - 0.5f * cn;             // Hann
            int q = f * HOP + n - 128;
            int xi = q < 0 ? -q : (q >= LX ? (2 * LX - 2 - q) : q);  // reflect
            xw[n] = x[b * LX + xi] * win;
        }
        __syncthreads();
        float c = 1.f, s = 0.f;
        float re = 0.f, im = 0.f;
        float reN = 0.f, sgn = 1.f;
        for (int n = 0; n < NFFT; ++n) {
            float v = xw[n];
            re += v * c;
            im += v * s;
            reN += v * sgn;
            sgn = -sgn;
            float t = c * c1 - s * s1;
            s = c * s1 + s * c1;
            c = t;
        }
        acck += sqrtf(re * re + im * im);
        accN += fabsf(reN);
    }
    float* prow = part + (b * NFG + g) * PART_STRIDE;
    prow[k] = acck;
    if (tid == 0) prow[128] = accN;
}

// ---------------- Gating MLP + top-2 softmax ----------------
__global__ __launch_bounds__(256) void gating_kernel(
    const float* __restrict__ part,
    const float* __restrict__ Wg1, const float* __restrict__ bg1,
    const float* __restrict__ Wg2, const float* __restrict__ bg2,
    const float* __restrict__ Wg3, const float* __restrict__ bg3,
    int* __restrict__ inds, float* __restrict__ wts) {
    __shared__ float pl[NBINS];
    __shared__ float h1[256];
    __shared__ float h2[128];
    __shared__ float lg[NE];
    const int b = blockIdx.x, tid = threadIdx.x;

    if (tid < NBINS) {
        float s = 0.f;
        for (int g = 0; g < NFG; ++g)
            s += part[(b * NFG + g) * PART_STRIDE + tid];
        pl[tid] = s * (1.0f / (float)NFRAMES);
    }
    __syncthreads();
    {
        float s = bg1[tid];
        for (int k = 0; k < NBINS; ++k) s += pl[k] * Wg1[k * 256 + tid];
        h1[tid] = fmaxf(s, 0.f);
    }
    __syncthreads();
    if (tid < 128) {
        float s = bg2[tid];
        for (int k = 0; k < 256; ++k) s += h1[k] * Wg2[k * 128 + tid];
        h2[tid] = fmaxf(s, 0.f);
    }
    __syncthreads();
    if (tid < NE) {
        float s = bg3[tid];
        for (int k = 0; k < 128; ++k) s += h2[k] * Wg3[k * NE + tid];
        lg[tid] = s;
    }
    __syncthreads();
    if (tid == 0) {
        int i0 = 0;
        float v0 = lg[0];
        for (int i = 1; i < NE; ++i)
            if (lg[i] > v0) { v0 = lg[i]; i0 = i; }
        int i1 = -1;
        float v1 = -3.0e38f;
        for (int i = 0; i < NE; ++i) {
            if (i == i0) continue;
            if (lg[i] > v1) { v1 = lg[i]; i1 = i; }
        }
        float e1 = expf(v1 - v0);
        float w0 = 1.f / (1.f + e1);
        inds[b * 2 + 0] = i0;
        inds[b * 2 + 1] = i1;
        wts[b * 2 + 0] = w0;
        wts[b * 2 + 1] = e1 * w0;
    }
}

// ---------------- Expert two-conv path, top-2 dispatched ----------------
// grid (u-tiles=8 of 128, branch=3, batch=64), 512 threads (8 waves).
// Lane keeps its 16-float x-window in REGISTERS for the whole block; phase A
// has no vector loads (weights wave-uniform -> s_load). Wave w owns c2 block
// {8w..8w+7}; lane owns 2 consecutive u. All LDS patterns dense (no swizzle);
// the 5th conv tap comes from the duplicated edge array hx2 (stride-1 reads).
#define UT 128
#define CCH 16
#define HROW 256     // words per hl row (64 groups * 4)
#define H2ROW 66

template <int KSZ>
__device__ __attribute__((always_inline)) void expert_body(
    const float* __restrict__ x,
    const float* __restrict__ wa, const float* __restrict__ ba,
    const float* __restrict__ wTbr, const float* __restrict__ bb,
    const int* __restrict__ inds, const float* __restrict__ wts,
    float* __restrict__ out, int br, float* hl, float* hx2) {
    const int u0 = blockIdx.x * UT;
    const int b = blockIdx.z;
    const int tid = threadIdx.x;
    const int lane = tid & 63;
    const int wv = __builtin_amdgcn_readfirstlane(tid >> 6);  // c2 block
    const int pad = KSZ >> 1;

    const int t0 = 2 * u0 - 1;          // first h position (may be -1)
    const int x0 = 2 * t0 - pad;        // first x index of the tile

    // persistent per-lane x window: x[x0 + 8*lane .. +15]
    float xv[16];
    {
        const float* xp = x + b * LX;
        int base = x0 + 8 * lane;
#pragma unroll
        for (int ii = 0; ii < 16; ++ii) {
            int xi = base + ii;
            xv[ii] = (xi >= 0 && xi < LX) ? xp[xi] : 0.f;
        }
    }

    float fin[8][2];
#pragma unroll
    for (int j = 0; j < 8; ++j) { fin[j][0] = 0.f; fin[j][1] = 0.f; }

#pragma unroll 1
    for (int slot = 0; slot < 2; ++slot) {
        const int e = __builtin_amdgcn_readfirstlane(inds[b * 2 + slot]);
        const float wj = wts[b * 2 + slot];
        const float* wTe = wTbr + e * 12288 + wv * 8;   // + cl*192 + i*64 + j

        float acc[8][2];
#pragma unroll
        for (int j = 0; j < 8; ++j) {
            float bbv = bb[e * NCH + wv * 8 + j];       // uniform -> s_load
            acc[j][0] = bbv;
            acc[j][1] = bbv;
        }

#pragma unroll 1
        for (int c0 = 0; c0 < NCH; c0 += CCH) {
            __syncthreads();   // protect LDS from previous chunk's readers

            // phase A: first conv + relu. wave -> cl (uniform), lane -> group.
#pragma unroll
            for (int it = 0; it < 2; ++it) {
                const int cl = wv + 8 * it;             // scalar
                const float* war = wa + (e * NCH + c0 + cl) * KSZ;
                float wr[KSZ];
#pragma unroll
                for (int i = 0; i < KSZ; ++i) wr[i] = war[i];   // s_load
                float bv = ba[e * NCH + c0 + cl];
                float hm[4];
#pragma unroll
                for (int m = 0; m < 4; ++m) {
                    float s = bv;
#pragma unroll
                    for (int i = 0; i < KSZ; ++i) s += wr[i] * xv[2 * m + i];
                    hm[m] = fmaxf(s, 0.f);
                }
                if (t0 < 0 && lane == 0) hm[0] = 0.f;   // h[-1]=0 (tile 0)
                float4 hv;
                hv.x = hm[0]; hv.y = hm[1]; hv.z = hm[2]; hv.w = hm[3];
                *(float4*)&hl[cl * HROW + 4 * lane] = hv;
                hx2[cl * H2ROW + lane] = hm[0];
                if (lane == 63) {                        // position p=256
                    float s = bv;
#pragma unroll
                    for (int i = 0; i < KSZ; ++i) s += wr[i] * xv[8 + i];
                    hx2[cl * H2ROW + 64] = fmaxf(s, 0.f);
                }
            }
            __syncthreads();

            // phase C: 8 c2 x 2 u per lane; weights via scalar loads.
#pragma unroll 2
            for (int cl = 0; cl < CCH; ++cl) {
                const float* wrow = wTe + (c0 + cl) * 192;
                float sw0[8], sw1[8], sw2[8];
#pragma unroll
                for (int j = 0; j < 8; ++j) {
                    sw0[j] = wrow[j];
                    sw1[j] = wrow[64 + j];
                    sw2[j] = wrow[128 + j];
                }
                float4 ha = *(const float4*)&hl[cl * HROW + 4 * lane];
                float hx = hx2[cl * H2ROW + lane + 1];
#pragma unroll
                for (int j = 0; j < 8; ++j) {
                    acc[j][0] += sw0[j] * ha.x + sw1[j] * ha.y + sw2[j] * ha.z;
                    acc[j][1] += sw0[j] * ha.z + sw1[j] * ha.w + sw2[j] * hx;
                }
            }
        }

#pragma unroll
        for (int j = 0; j < 8; ++j) {
            fin[j][0] += wj * fmaxf(acc[j][0], 0.f);
            fin[j][1] += wj * fmaxf(acc[j][1], 0.f);
        }
    }

#pragma unroll
    for (int j = 0; j < 8; ++j) {
        int c2 = wv * 8 + j;
        long row = (long)(b * 192 + br * 64 + c2) * LY;
        float2 o;
        o.x = fin[j][0];
        o.y = fin[j][1];
        *(float2*)&out[row + u0 + 2 * lane] = o;
    }
}

__global__ __launch_bounds__(512, 2) void expert_kernel(
    const float* __restrict__ x,
    const float* __restrict__ wa3, const float* __restrict__ ba3,
    const float* __restrict__ bb3,
    const float* __restrict__ wa5, const float* __restrict__ ba5,
    const float* __restrict__ bb5,
    const float* __restrict__ wa7, const float* __restrict__ ba7,
    const float* __restrict__ bb7,
    const float* __restrict__ wT,
    const int* __restrict__ inds, const float* __restrict__ wts,
    float* __restrict__ out) {
    __shared__ float hl[CCH * HROW];       // 16 KB
    __shared__ float hx2[CCH * H2ROW];     // 4.2 KB

    const int br = blockIdx.y;
    if (br == 0)
        expert_body<3>(x, wa3, ba3, wT, bb3, inds, wts, out, 0, hl, hx2);
    else if (br == 1)
        expert_body<5>(x, wa5, ba5, wT + WT_PER, bb5, inds, wts, out, 1, hl, hx2);
    else
        expert_body<7>(x, wa7, ba7, wT + 2 * WT_PER, bb7, inds, wts, out, 2, hl, hx2);
}

extern "C" void kernel_launch(void* const* d_in, const int* in_sizes, int n_in,
                              void* d_out, int out_size, void* d_ws, size_t ws_size,
                              hipStream_t stream) {
    const float* x   = (const float*)d_in[0];
    const float* Wg1 = (const float*)d_in[1];
    const float* bg1 = (const float*)d_in[2];
    const float* Wg2 = (const float*)d_in[3];
    const float* bg2 = (const float*)d_in[4];
    const float* Wg3 = (const float*)d_in[5];
    const float* bg3 = (const float*)d_in[6];
    const float* wa3 = (const float*)d_in[7];
    const float* ba3 = (const float*)d_in[8];
    const float* wb3 = (const float*)d_in[9];
    const float* bb3 = (const float*)d_in[10];
    const float* wa5 = (const float*)d_in[11];
    const float* ba5 = (const float*)d_in[12];
    const float* wb5 = (const float*)d_in[13];
    const float* bb5 = (const float*)d_in[14];
    const float* wa7 = (const float*)d_in[15];
    const float* ba7 = (const float*)d_in[16];
    const float* wb7 = (const float*)d_in[17];
    const float* bb7 = (const float*)d_in[18];

    float* part = (float*)d_ws;
    float* wT = (float*)((char*)d_ws + WT_OFF);
    int* inds = (int*)((char*)d_ws + IW_OFF);
    float* wts = (float*)((char*)d_ws + IW_OFF + 512);

    stft_kernel<<<dim3(NFG, NB), 128, 0, stream>>>(x, wb3, wb5, wb7, wT, part);
    gating_kernel<<<NB, 256, 0, stream>>>(part, Wg1, bg1, Wg2, bg2, Wg3, bg3,
                                          inds, wts);
    expert_kernel<<<dim3(LY / UT, NBR, NB), 512, 0, stream>>>(
        x, wa3, ba3, bb3, wa5, ba5, bb5, wa7, ba7, bb7, wT,
        inds, wts, (float*)d_out);
}

// Round 9
// 200.464 us; speedup vs baseline: 3.4350x; 1.6935x over previous
//
#include <hip/hip_runtime.h>
#include <math.h>

#define NFFT 256
#define NBINS 129
#define HOP 64
#define NFRAMES 65
#define NB 64
#define LX 4096
#define LH 2048
#define LY 1024
#define NCH 64
#define NBR 3
#define NE 8

#define NFG 13                      // frame groups (5 frames each)
#define PART_STRIDE 132
#define WTF_OFF 440320              // byte offset of bf16 wTf in ws
#define WTF_PER 98304               // bf16 elements per branch (8e*4mw*3i*2kb*64lane*8j)
#define IW_OFF 1031168              // inds/wts offset

typedef __attribute__((ext_vector_type(8))) short short8;   // 8 bf16
typedef __attribute__((ext_vector_type(4))) float floatx4;

__device__ __forceinline__ unsigned short bf16r(float f) {  // round-nearest-even
    unsigned u = __builtin_bit_cast(unsigned, f);
    u += 0x7FFFu + ((u >> 16) & 1u);
    return (unsigned short)(u >> 16);
}

// ---------------- STFT partial magnitudes + bf16 A-fragment build ----------
// grid (13 frame-groups, 64 batch), 128 threads.
__global__ __launch_bounds__(128) void stft_kernel(
    const float* __restrict__ x,
    const float* __restrict__ wb3, const float* __restrict__ wb5,
    const float* __restrict__ wb7, unsigned short* __restrict__ wTf,
    float* __restrict__ part) {
    __shared__ float xw[NFFT];
    const int g = blockIdx.x, b = blockIdx.y;
    const int tid = threadIdx.x;

    // build wTf[br][e][mw][i][kb][lane][j] in MFMA A-fragment order:
    //   c2 = mw*16 + (lane&15), cl = kb*32 + (lane>>4)*8 + j
    {
        int bid = b * NFG + g;
        for (int fi = bid * 128 + tid; fi < 3 * WTF_PER; fi += NB * NFG * 128) {
            int br = fi / WTF_PER, r = fi % WTF_PER;
            int e = r / 12288;
            int r2 = r % 12288;
            int mw = r2 / 3072;
            int r3 = r2 % 3072;
            int i = r3 / 1024;
            int r4 = r3 % 1024;
            int kb = r4 / 512;
            int r5 = r4 % 512;
            int lane = r5 / 8, j = r5 % 8;
            int c2 = mw * 16 + (lane & 15);
            int cl = kb * 32 + (lane >> 4) * 8 + j;
            const float* src = (br == 0) ? wb3 : (br == 1) ? wb5 : wb7;
            wTf[fi] = bf16r(src[((e * 64 + c2) * 64 + cl) * 3 + i]);
        }
    }

    const int k = tid;
    float ang = (float)(2.0 * 3.14159265358979323846 / 256.0) * (float)k;
    float s1, c1;
    sincosf(ang, &s1, &c1);

    float acck = 0.f, accN = 0.f;
    for (int f0 = 0; f0 < 5; ++f0) {
        int f = g * 5 + f0;
        __syncthreads();
        for (int n = tid; n < NFFT; n += 128) {
            float a2 = (float)(2.0 * 3.14159265358979323846 / 256.0) * (float)n;
            float sn, cn;
            sincosf(a2, &sn, &cn);
            float win = 0.5f - 0.5f * cn;             // Hann
            int q = f * HOP + n - 128;
            int xi = q < 0 ? -q : (q >= LX ? (2 * LX - 2 - q) : q);  // reflect
            xw[n] = x[b * LX + xi] * win;
        }
        __syncthreads();
        float c = 1.f, s = 0.f;
        float re = 0.f, im = 0.f;
        float reN = 0.f, sgn = 1.f;
        for (int n = 0; n < NFFT; ++n) {
            float v = xw[n];
            re += v * c;
            im += v * s;
            reN += v * sgn;
            sgn = -sgn;
            float t = c * c1 - s * s1;
            s = c * s1 + s * c1;
            c = t;
        }
        acck += sqrtf(re * re + im * im);
        accN += fabsf(reN);
    }
    float* prow = part + (b * NFG + g) * PART_STRIDE;
    prow[k] = acck;
    if (tid == 0) prow[128] = accN;
}

// ---------------- Gating MLP + top-2 softmax ----------------
__global__ __launch_bounds__(256) void gating_kernel(
    const float* __restrict__ part,
    const float* __restrict__ Wg1, const float* __restrict__ bg1,
    const float* __restrict__ Wg2, const float* __restrict__ bg2,
    const float* __restrict__ Wg3, const float* __restrict__ bg3,
    int* __restrict__ inds, float* __restrict__ wts) {
    __shared__ float pl[NBINS];
    __shared__ float h1[256];
    __shared__ float h2[128];
    __shared__ float lg[NE];
    const int b = blockIdx.x, tid = threadIdx.x;

    if (tid < NBINS) {
        float s = 0.f;
        for (int g = 0; g < NFG; ++g)
            s += part[(b * NFG + g) * PART_STRIDE + tid];
        pl[tid] = s * (1.0f / (float)NFRAMES);
    }
    __syncthreads();
    {
        float s = bg1[tid];
        for (int k = 0; k < NBINS; ++k) s += pl[k] * Wg1[k * 256 + tid];
        h1[tid] = fmaxf(s, 0.f);
    }
    __syncthreads();
    if (tid < 128) {
        float s = bg2[tid];
        for (int k = 0; k < 256; ++k) s += h1[k] * Wg2[k * 128 + tid];
        h2[tid] = fmaxf(s, 0.f);
    }
    __syncthreads();
    if (tid < NE) {
        float s = bg3[tid];
        for (int k = 0; k < 128; ++k) s += h2[k] * Wg3[k * NE + tid];
        lg[tid] = s;
    }
    __syncthreads();
    if (tid == 0) {
        int i0 = 0;
        float v0 = lg[0];
        for (int i = 1; i < NE; ++i)
            if (lg[i] > v0) { v0 = lg[i]; i0 = i; }
        int i1 = -1;
        float v1 = -3.0e38f;
        for (int i = 0; i < NE; ++i) {
            if (i == i0) continue;
            if (lg[i] > v1) { v1 = lg[i]; i1 = i; }
        }
        float e1 = expf(v1 - v0);
        float w0 = 1.f / (1.f + e1);
        inds[b * 2 + 0] = i0;
        inds[b * 2 + 1] = i1;
        wts[b * 2 + 0] = w0;
        wts[b * 2 + 1] = e1 * w0;
    }
}

// ---------------- Expert path: fp32 conv1 -> bf16 MFMA conv2 ----------------
// grid (u-tiles=8 of 128, branch=3, batch=64), 512 threads (8 waves).
// Phase A: lane<->cl (dense b16 writes), x via wave-uniform scalar loads,
// h -> bf16 tile hp[tl][cl] (258 x 68 shorts, 136B rows).
// Phase C: wave (mw,nh): 4 N-tiles x 3 taps x 2 K-blocks mfma 16x16x32 bf16;
// B-frags 2x ds_read_b64 (2-way, free); A-frags one 16B global load from wTf.
#define UT 128
#define HPR 68           // shorts per hp row (64 + 4 pad)
#define HROWS 258

template <int KSZ>
__device__ __attribute__((always_inline)) void expert_body(
    const float* __restrict__ x,
    const float* __restrict__ wa, const float* __restrict__ ba,
    const float* __restrict__ bb, const unsigned short* __restrict__ wTfbr,
    const int* __restrict__ inds, const float* __restrict__ wts,
    float* __restrict__ out, int br, short* hp) {
    const int u0 = blockIdx.x * UT;
    const int b = blockIdx.z;
    const int tid = threadIdx.x;
    const int lane = tid & 63;
    const int quad = lane >> 4;
    const int l15 = lane & 15;
    const int wv = __builtin_amdgcn_readfirstlane(tid >> 6);
    const int mw = wv & 3;           // M-tile (c2 block of 16)
    const int nh = wv >> 2;          // N-half (4 N-tiles each)
    const int pad = KSZ >> 1;
    const int t0 = 2 * u0 - 1;
    const int x0 = 2 * t0 - pad;

    const float* xp = x + b * LX;

    float fin[4][4];
#pragma unroll
    for (int q = 0; q < 4; ++q)
#pragma unroll
        for (int r = 0; r < 4; ++r) fin[q][r] = 0.f;

#pragma unroll 1
    for (int slot = 0; slot < 2; ++slot) {
        const int e = __builtin_amdgcn_readfirstlane(inds[b * 2 + slot]);
        const float wj = wts[b * 2 + slot];

        // first-conv weights for this lane's channel (cl = lane)
        float wr[KSZ];
#pragma unroll
        for (int i = 0; i < KSZ; ++i) wr[i] = wa[(e * NCH + lane) * KSZ + i];
        const float bv = ba[e * NCH + lane];

        __syncthreads();   // protect hp from previous slot's phase C readers

        // ---- phase A: h rows tl = 0..257 ----
#pragma unroll 1
        for (int it = 0; it < 9; ++it) {
            int tb = wv + 8 * it;            // wave-uniform t-block (4 rows)
            if (tb > 64) break;
            int base = x0 + 8 * tb;          // wave-uniform x base
            float xr[16];
            if (base >= 0 && base + 15 < LX) {
#pragma unroll
                for (int ii = 0; ii < 16; ++ii) xr[ii] = xp[base + ii];
            } else {
#pragma unroll
                for (int ii = 0; ii < 16; ++ii) {
                    int xi = base + ii;
                    xr[ii] = (xi >= 0 && xi < LX) ? xp[xi] : 0.f;
                }
            }
#pragma unroll
            for (int m = 0; m < 4; ++m) {
                int tl = 4 * tb + m;
                if (tl > 257) continue;
                int t = t0 + tl;
                float s = bv;
#pragma unroll
                for (int i = 0; i < KSZ; ++i) s += wr[i] * xr[2 * m + i];
                float h = (t >= 0 && t < LH) ? fmaxf(s, 0.f) : 0.f;
                hp[tl * HPR + lane] = (short)bf16r(h);
            }
        }
        __syncthreads();

        // ---- phase C: MFMA GEMM ----
        // bias per lane for C-layout rows: c2 = mw*16 + quad*4 + r
        float br4[4];
#pragma unroll
        for (int r = 0; r < 4; ++r)
            br4[r] = bb[e * NCH + mw * 16 + quad * 4 + r];

        // A-frags: wTf + e*12288 + mw*3072 + i*1024 + kb*512 + lane*8
        short8 af[3][2];
        {
            const unsigned short* wbase =
                wTfbr + e * 12288 + mw * 3072 + lane * 8;
#pragma unroll
            for (int i = 0; i < 3; ++i)
#pragma unroll
                for (int kb = 0; kb < 2; ++kb)
                    af[i][kb] = *(const short8*)&wbase[i * 1024 + kb * 512];
        }

#pragma unroll 1
        for (int q = 0; q < 4; ++q) {
            int nt = nh * 4 + q;
            int nb = nt * 16 + l15;          // local u (B-layout n = lane&15)
            floatx4 acc = {br4[0], br4[1], br4[2], br4[3]};
#pragma unroll
            for (int i = 0; i < 3; ++i) {
                int tl = 2 * nb + i;         // B row
#pragma unroll
                for (int kb = 0; kb < 2; ++kb) {
                    int sb = tl * HPR + kb * 32 + quad * 8;
                    union { short8 v; unsigned long long q2[2]; } B;
                    B.q2[0] = *(const unsigned long long*)&hp[sb];
                    B.q2[1] = *(const unsigned long long*)&hp[sb + 4];
                    acc = __builtin_amdgcn_mfma_f32_16x16x32_bf16(
                        af[i][kb], B.v, acc, 0, 0, 0);
                }
            }
#pragma unroll
            for (int r = 0; r < 4; ++r)
                fin[q][r] += wj * fmaxf(acc[r], 0.f);
        }
    }

    // ---- store: lane holds col n = l15, rows c2 = mw*16 + quad*4 + r ----
#pragma unroll
    for (int q = 0; q < 4; ++q) {
        int u = u0 + (nh * 4 + q) * 16 + l15;
#pragma unroll
        for (int r = 0; r < 4; ++r) {
            int c2 = mw * 16 + quad * 4 + r;
            out[(long)(b * 192 + br * 64 + c2) * LY + u] = fin[q][r];
        }
    }
}

__global__ __launch_bounds__(512, 2) void expert_kernel(
    const float* __restrict__ x,
    const float* __restrict__ wa3, const float* __restrict__ ba3,
    const float* __restrict__ bb3,
    const float* __restrict__ wa5, const float* __restrict__ ba5,
    const float* __restrict__ bb5,
    const float* __restrict__ wa7, const float* __restrict__ ba7,
    const float* __restrict__ bb7,
    const unsigned short* __restrict__ wTf,
    const int* __restrict__ inds, const float* __restrict__ wts,
    float* __restrict__ out) {
    __shared__ short hp[HROWS * HPR];      // 35.1 KB

    const int br = blockIdx.y;
    if (br == 0)
        expert_body<3>(x, wa3, ba3, bb3, wTf, inds, wts, out, 0, hp);
    else if (br == 1)
        expert_body<5>(x, wa5, ba5, bb5, wTf + WTF_PER, inds, wts, out, 1, hp);
    else
        expert_body<7>(x, wa7, ba7, bb7, wTf + 2 * WTF_PER, inds, wts, out, 2, hp);
}

extern "C" void kernel_launch(void* const* d_in, const int* in_sizes, int n_in,
                              void* d_out, int out_size, void* d_ws, size_t ws_size,
                              hipStream_t stream) {
    const float* x   = (const float*)d_in[0];
    const float* Wg1 = (const float*)d_in[1];
    const float* bg1 = (const float*)d_in[2];
    const float* Wg2 = (const float*)d_in[3];
    const float* bg2 = (const float*)d_in[4];
    const float* Wg3 = (const float*)d_in[5];
    const float* bg3 = (const float*)d_in[6];
    const float* wa3 = (const float*)d_in[7];
    const float* ba3 = (const float*)d_in[8];
    const float* wb3 = (const float*)d_in[9];
    const float* bb3 = (const float*)d_in[10];
    const float* wa5 = (const float*)d_in[11];
    const float* ba5 = (const float*)d_in[12];
    const float* wb5 = (const float*)d_in[13];
    const float* bb5 = (const float*)d_in[14];
    const float* wa7 = (const float*)d_in[15];
    const float* ba7 = (const float*)d_in[16];
    const float* wb7 = (const float*)d_in[17];
    const float* bb7 = (const float*)d_in[18];

    float* part = (float*)d_ws;
    unsigned short* wTf = (unsigned short*)((char*)d_ws + WTF_OFF);
    int* inds = (int*)((char*)d_ws + IW_OFF);
    float* wts = (float*)((char*)d_ws + IW_OFF + 512);

    stft_kernel<<<dim3(NFG, NB), 128, 0, stream>>>(x, wb3, wb5, wb7, wTf, part);
    gating_kernel<<<NB, 256, 0, stream>>>(part, Wg1, bg1, Wg2, bg2, Wg3, bg3,
                                          inds, wts);
    expert_kernel<<<dim3(LY / UT, NBR, NB), 512, 0, stream>>>(
        x, wa3, ba3, bb3, wa5, ba5, bb5, wa7, ba7, bb7, wTf,
        inds, wts, (float*)d_out);
}